// Round 2
// baseline (478.766 us; speedup 1.0000x reference)
//
#include <hip/hip_runtime.h>
#include <hip/hip_bf16.h>
#include <math.h>

// LSMDecoder: out = sigmoid(bias - wg*N*dist_gam - wd*N*dist_del), plus zd/gd_raw/dd_raw.
// x[i,j] = cvec_i - bco_j - N * dot(A_i, B_j), 512-dim fp16 stacks, fp32 MFMA accumulate.
// Diagonal overridden exactly. R2: global_load_lds(16B) + XOR-swizzled LDS in pair_kernel;
// gemm3 re-tiled 32x128 (768 blocks = 3/CU exactly).

#define NSZ 8192
#define DLAT 128

typedef _Float16 half8 __attribute__((ext_vector_type(8)));
typedef float f32x4 __attribute__((ext_vector_type(4)));

__device__ __forceinline__ void gl_lds16(const void* g, void* l) {
    __builtin_amdgcn_global_load_lds(
        (const __attribute__((address_space(1))) void*)g,
        (__attribute__((address_space(3))) void*)l, 16, 0, 0);
}

// ---------------- P1: column softmax of Wz/Wg/Wd (axis 0, 512 rows x 128 cols) -------------
__global__ void softmax_cols(const float* __restrict__ Wz, const float* __restrict__ Wg,
                             const float* __restrict__ Wd, float* __restrict__ T) {
    int col = blockIdx.x & 127;
    int m = blockIdx.x >> 7;
    const float* W = (m == 0) ? Wz : (m == 1 ? Wg : Wd);
    float* To = T + (size_t)m * 65536;
    int l = threadIdx.x;  // 64 threads = 1 wave
    float v[8];
    float mx = -3.4e38f;
    for (int i = 0; i < 8; ++i) {
        v[i] = W[(size_t)(i * 64 + l) * 128 + col];
        mx = fmaxf(mx, v[i]);
    }
    for (int off = 32; off; off >>= 1) mx = fmaxf(mx, __shfl_xor(mx, off));
    float s = 0.f;
    for (int i = 0; i < 8; ++i) { v[i] = expf(v[i] - mx); s += v[i]; }
    for (int off = 32; off; off >>= 1) s += __shfl_xor(s, off);
    float inv = 1.0f / s;
    for (int i = 0; i < 8; ++i) To[(size_t)(i * 64 + l) * 128 + col] = v[i] * inv;
}

// ---------------- P2: fp32 GEMM  [8192x512] @ [512x128] for zd / gd_raw / dd_raw -----------
// 32 rows x 128 cols per block -> 256 x 3 = 768 blocks = 3 blocks/CU. micro-tile 2x8.
__global__ __launch_bounds__(256) void gemm3(const float* __restrict__ z,
                                             const float* __restrict__ gamma,
                                             const float* __restrict__ delta,
                                             const float* __restrict__ T,
                                             float* __restrict__ outTail) {
    int m = blockIdx.y;
    const float* A = (m == 0) ? z : (m == 1 ? gamma : delta);
    const float* B = T + (size_t)m * 65536;
    float* C = outTail + (size_t)m * (NSZ * DLAT);
    int rowBase = blockIdx.x * 32;
    __shared__ float As[32 * 38];    // transposed: As[k*38 + row], even stride (aligned b64)
    __shared__ float Bs[32 * 132];   // Bs[k*132 + col], +4 pad
    int t = threadIdx.x;
    int cg = t & 15, rg = t >> 4;    // rg 0..15 -> 2 rows each; cg -> 8 cols
    float acc[2][8] = {};
    for (int kt = 0; kt < 16; ++kt) {
        int k0 = kt * 32;
        {   // stage A: 32 rows x 32 k, transposed
            int r = t >> 3, kk = (t & 7) * 4;
            float4 va = *(const float4*)(A + (size_t)(rowBase + r) * 512 + k0 + kk);
            As[(kk + 0) * 38 + r] = va.x; As[(kk + 1) * 38 + r] = va.y;
            As[(kk + 2) * 38 + r] = va.z; As[(kk + 3) * 38 + r] = va.w;
        }
        for (int i = 0; i < 4; ++i) {   // stage B: 32 k x 128 cols
            int lin = i * 1024 + t * 4;
            int kk = lin >> 7, col = lin & 127;
            *(float4*)(&Bs[kk * 132 + col]) = *(const float4*)(B + (size_t)(k0 + kk) * 128 + col);
        }
        __syncthreads();
        for (int kk = 0; kk < 32; ++kk) {
            float2 av = *(const float2*)(&As[kk * 38 + rg * 2]);
            float b0[8];
            *(float4*)b0 = *(const float4*)(&Bs[kk * 132 + cg * 8]);
            *(float4*)(b0 + 4) = *(const float4*)(&Bs[kk * 132 + cg * 8 + 4]);
            for (int c = 0; c < 8; ++c) {
                acc[0][c] = fmaf(av.x, b0[c], acc[0][c]);
                acc[1][c] = fmaf(av.y, b0[c], acc[1][c]);
            }
        }
        __syncthreads();
    }
    for (int r = 0; r < 2; ++r) {
        int row = rowBase + rg * 2 + r;
        float4 s0 = make_float4(acc[r][0], acc[r][1], acc[r][2], acc[r][3]);
        float4 s1 = make_float4(acc[r][4], acc[r][5], acc[r][6], acc[r][7]);
        *(float4*)(C + (size_t)row * 128 + cg * 8) = s0;
        *(float4*)(C + (size_t)row * 128 + cg * 8 + 4) = s1;
    }
}

// ---------------- P2b: build fp16 stacked A/B [8192x512] + per-row scalars ------------------
__global__ void build_stacks(const float* __restrict__ zd, const float* __restrict__ gdr,
                             const float* __restrict__ ddr, _Float16* __restrict__ Afp,
                             _Float16* __restrict__ Bfp, float* __restrict__ cvec,
                             float* __restrict__ bco, const float* __restrict__ pb,
                             const float* __restrict__ pwg, const float* __restrict__ pwd) {
    int i = blockIdx.x;    // 8192 rows
    int k = threadIdx.x;   // 128
    float zv = zd[(size_t)i * 128 + k];
    float g = gdr[(size_t)i * 128 + k] + 1e-16f;
    float d = ddr[(size_t)i * 128 + k] + 1e-16f;
    float z2 = zv * zv;
    float u = 1.0f / g, p = 1.0f / d;
    float v = zv * u, q = zv * p;
    float wg = *pwg, wd = *pwd, bias = *pb;
    _Float16* Ar = Afp + (size_t)i * 512;
    _Float16* Br = Bfp + (size_t)i * 512;
    Ar[k]       = (_Float16)(wg * u);
    Ar[128 + k] = (_Float16)(wg * v);
    Ar[256 + k] = (_Float16)(wd * z2);
    Ar[384 + k] = (_Float16)(wd * zv);
    Br[k]       = (_Float16)(z2);
    Br[128 + k] = (_Float16)(-2.0f * zv);
    Br[256 + k] = (_Float16)(p);
    Br[384 + k] = (_Float16)(-2.0f * q);
    float a = z2 * u, b = z2 * p;
    for (int off = 32; off; off >>= 1) { a += __shfl_down(a, off); b += __shfl_down(b, off); }
    __shared__ float sa[2], sb[2];
    if ((k & 63) == 0) { sa[k >> 6] = a; sb[k >> 6] = b; }
    __syncthreads();
    if (k == 0) {
        cvec[i] = bias - 8192.0f * wg * (sa[0] + sa[1]);
        bco[i] = 8192.0f * wd * (sb[0] + sb[1]);
    }
}

// ---------------- P3: fp16 MFMA pair kernel, 128x128 tile, K=512, fused sigmoid -------------
// LDS layout: per matrix 128 rows x 8 chunks of 16B, slot(r,q) = r*8 + (q ^ (r&7)).
// Staged via global_load_lds (wave-uniform LDS base + lane*16); lane fetches the
// permuted global chunk so the swizzle costs only VGPR address math.
__global__ __launch_bounds__(256) void pair_kernel(const _Float16* __restrict__ Afp,
                                                   const _Float16* __restrict__ Bfp,
                                                   const float* __restrict__ cvec,
                                                   const float* __restrict__ bco,
                                                   const float* __restrict__ pbias,
                                                   float* __restrict__ out) {
    // 8x8 supertile swizzle for L2 reuse
    int bid = blockIdx.x;
    int super = bid >> 6, within = bid & 63;
    int sy = super >> 3, sx = super & 7;
    int by = sy * 8 + (within >> 3), bx = sx * 8 + (within & 7);
    int iBase = by * 128, jBase = bx * 128;

    __shared__ _Float16 As[128 * 64];  // 16 KB, XOR-swizzled chunks
    __shared__ _Float16 Bs[128 * 64];
    int t = threadIdx.x;
    int l = t & 63, w = t >> 6;
    int wm = (w >> 1) * 64, wn = (w & 1) * 64;
    int lc = l & 15, lq = l >> 4;
    f32x4 acc[4][4] = {};

    // per-lane staging geometry (constant across kt)
    int srow = l >> 3;                 // 0..7 row within the 8-row group
    int sq = (l & 7) ^ srow;           // permuted chunk index within the row
    f32x4* accp = &acc[0][0];
    (void)accp;

    for (int kt = 0; kt < 8; ++kt) {
        int k0 = kt * 64;
        for (int s = 0; s < 4; ++s) {
            int rr = (w * 4 + s) * 8 + srow;                     // tile row 0..127
            const _Float16* ga = Afp + (size_t)(iBase + rr) * 512 + k0 + sq * 8;
            const _Float16* gb = Bfp + (size_t)(jBase + rr) * 512 + k0 + sq * 8;
            gl_lds16(ga, &As[(w * 4 + s) * 512]);
            gl_lds16(gb, &Bs[(w * 4 + s) * 512]);
        }
        __syncthreads();   // drains vmcnt -> staged data visible
        for (int ks = 0; ks < 2; ++ks) {
            half8 af[4], bf[4];
            for (int mi = 0; mi < 4; ++mi) {
                int r = wm + mi * 16 + lc;
                int q = ks * 4 + lq;
                af[mi] = *(const half8*)(&As[((r << 3) + (q ^ (r & 7))) << 3]);
            }
            for (int ni = 0; ni < 4; ++ni) {
                int r = wn + ni * 16 + lc;
                int q = ks * 4 + lq;
                bf[ni] = *(const half8*)(&Bs[((r << 3) + (q ^ (r & 7))) << 3]);
            }
            for (int mi = 0; mi < 4; ++mi)
                for (int ni = 0; ni < 4; ++ni)
                    acc[mi][ni] = __builtin_amdgcn_mfma_f32_16x16x32_f16(af[mi], bf[ni],
                                                                         acc[mi][ni], 0, 0, 0);
        }
        __syncthreads();
    }

    float bias = *pbias;
    float civ[4][4], bjv[4];
    for (int mi = 0; mi < 4; ++mi)
        for (int r = 0; r < 4; ++r)
            civ[mi][r] = cvec[iBase + wm + mi * 16 + lq * 4 + r];
    for (int ni = 0; ni < 4; ++ni) bjv[ni] = bco[jBase + wn + ni * 16 + lc];

    for (int mi = 0; mi < 4; ++mi) {
        for (int ni = 0; ni < 4; ++ni) {
            for (int r = 0; r < 4; ++r) {
                int i = iBase + wm + mi * 16 + lq * 4 + r;   // C/D: row = quad*4+reg
                int j = jBase + wn + ni * 16 + lc;           // C/D: col = lane&15
                float x = civ[mi][r] - bjv[ni] - 8192.0f * acc[mi][ni][r];
                if (i == j) x = bias;                        // exact diagonal (dist == 0)
                out[(size_t)i * NSZ + j] = 1.0f / (1.0f + expf(-x));
            }
        }
    }
}

extern "C" void kernel_launch(void* const* d_in, const int* in_sizes, int n_in,
                              void* d_out, int out_size, void* d_ws, size_t ws_size,
                              hipStream_t stream) {
    const float* z = (const float*)d_in[0];
    const float* gamma = (const float*)d_in[1];
    const float* delta = (const float*)d_in[2];
    const float* Wz = (const float*)d_in[3];
    const float* Wg = (const float*)d_in[4];
    const float* Wd = (const float*)d_in[5];
    const float* pb = (const float*)d_in[6];
    const float* pwg = (const float*)d_in[7];
    const float* pwd = (const float*)d_in[8];

    float* out = (float*)d_out;
    float* zd_out = out + (size_t)NSZ * NSZ;
    float* gd_out = zd_out + (size_t)NSZ * DLAT;
    float* dd_out = gd_out + (size_t)NSZ * DLAT;

    float* wsf = (float*)d_ws;
    float* T = wsf;                       // 3*512*128 f32 = 786 KB
    float* cvec = wsf + 196608;           // 8192
    float* bco = cvec + 8192;             // 8192
    _Float16* Afp = (_Float16*)(bco + 8192);          // 8192*512 fp16 = 8 MB
    _Float16* Bfp = Afp + (size_t)NSZ * 512;          // 8 MB

    softmax_cols<<<384, 64, 0, stream>>>(Wz, Wg, Wd, T);
    gemm3<<<dim3(256, 3), 256, 0, stream>>>(z, gamma, delta, T, zd_out);
    build_stacks<<<NSZ, 128, 0, stream>>>(zd_out, gd_out, dd_out, Afp, Bfp, cvec, bco,
                                          pb, pwg, pwd);
    pair_kernel<<<4096, 256, 0, stream>>>(Afp, Bfp, cvec, bco, pb, out);
}